// Round 13
// baseline (211.066 us; speedup 1.0000x reference)
//
#include <hip/hip_runtime.h>
#include <hip/hip_bf16.h>
#include <math.h>

#define N_SEQ 4096
#define DIM   1024
#define NHEAD 16
#define HDIM  64
#define E3    3072

typedef short bf16x8 __attribute__((ext_vector_type(8)));
typedef float f32x4  __attribute__((ext_vector_type(4)));
typedef unsigned int u32;

#if __has_builtin(__builtin_amdgcn_exp2f)
#define EXP2(x) __builtin_amdgcn_exp2f(x)   // raw v_exp_f32; exp2(-inf)=0
#else
#define EXP2(x) exp2f(x)
#endif

// HW sin/cos: v_sin_f32/v_cos_f32 take REVOLUTIONS (sin(2*pi*x)); reduce
// with fract first. 4 VALU per (sin,cos) pair vs ~60 for OCML sincosf.
#if __has_builtin(__builtin_amdgcn_sinf) && __has_builtin(__builtin_amdgcn_cosf)
__device__ __forceinline__ void hsincos_rev(float rev, float* s, float* c) {
    const float t = rev - floorf(rev);
    *s = __builtin_amdgcn_sinf(t);
    *c = __builtin_amdgcn_cosf(t);
}
#else
__device__ __forceinline__ void hsincos_rev(float rev, float* s, float* c) {
    sincosf(rev * 6.2831853071795865f, s, c);
}
#endif

__device__ __forceinline__ float bf2f(unsigned short u) {
    union { unsigned int i; float f; } x; x.i = ((unsigned int)u) << 16; return x.f;
}
__device__ __forceinline__ unsigned short f2bf(float f) {
    union { float f; unsigned int i; } x; x.f = f;
    unsigned int r = x.i + 0x7FFF + ((x.i >> 16) & 1);   // round-to-nearest-even
    return (unsigned short)(r >> 16);
}
// cheap pack (round-half-up in magnitude, <=1 ulp, sign-safe): 2 VALU ops
__device__ __forceinline__ unsigned short f2bf_fast(float f) {
    union { float f; unsigned int i; } x; x.f = f;
    return (unsigned short)((x.i + 0x8000u) >> 16);
}
__device__ __forceinline__ f32x4 mfma16(bf16x8 a, bf16x8 b, f32x4 c) {
    return __builtin_amdgcn_mfma_f32_16x16x32_bf16(a, b, c, 0, 0, 0);
}
// async global->LDS, 16B per lane; LDS dest = wave-uniform base + lane*16
__device__ __forceinline__ void gload_lds16(const unsigned short* g, unsigned short* l) {
    __builtin_amdgcn_global_load_lds(
        (const __attribute__((address_space(1))) u32*)g,
        (__attribute__((address_space(3))) u32*)l, 16, 0, 0);
}

// local (per-block) dtype probe
__device__ __forceinline__ int probe_isf32(const unsigned short* __restrict__ X) {
    __shared__ int cnt;
    if (threadIdx.x == 0) cnt = 0;
    __syncthreads();
    int bad = 0;
    for (int i = threadIdx.x; i < 4096; i += 256) {
        float v = bf2f(X[i]);
        if (!(fabsf(v) < 1e10f)) bad = 1;
    }
    if (bad) atomicAdd(&cnt, 1);
    __syncthreads();
    return cnt > 0;
}

// ---------------------------------------------------------------------------
// Kernel 0: fused prep (proven): local detect, convert only if fp32.
// ---------------------------------------------------------------------------
__global__ __launch_bounds__(256)
void prep_kernel(const void* __restrict__ X, const void* __restrict__ Wq,
                 const void* __restrict__ Wo,
                 unsigned short* __restrict__ Xb, unsigned short* __restrict__ Wqb,
                 unsigned short* __restrict__ Wob,
                 int* __restrict__ flag)
{
    const int isf32 = probe_isf32((const unsigned short*)X);
    if (blockIdx.x == 0 && threadIdx.x == 0) *flag = isf32;
    if (!isf32) return;

    const int nX4  = (N_SEQ * DIM) >> 2;
    const int nWq4 = (E3 * DIM) >> 2;
    const int nWo4 = (DIM * DIM) >> 2;
    const int total = nX4 + nWq4 + nWo4;
    const int stride = gridDim.x * blockDim.x;
    for (int i = blockIdx.x * blockDim.x + threadIdx.x; i < total; i += stride) {
        const float4* src; ushort4* dst; int j = i;
        if (j < nX4)                { src = (const float4*)X  + j;  dst = (ushort4*)Xb  + j; }
        else if ((j -= nX4) < nWq4) { src = (const float4*)Wq + j;  dst = (ushort4*)Wqb + j; }
        else { j -= nWq4;             src = (const float4*)Wo + j;  dst = (ushort4*)Wob + j; }
        float4 v = *src;
        ushort4 u;
        u.x = f2bf(v.x); u.y = f2bf(v.y); u.z = f2bf(v.z); u.w = f2bf(v.w);
        *dst = u;
    }
}

// ---------------------------------------------------------------------------
// Kernel 1: QKV projection + fused RoPE (r11 loop; epilogue now uses HW
// sin/cos in revolutions + fast bf16 pack).
// ---------------------------------------------------------------------------
__global__ __launch_bounds__(256)
void qkv_mfma_kernel(const void* __restrict__ Xo, const unsigned short* __restrict__ Xc,
                     const void* __restrict__ Wo_, const unsigned short* __restrict__ Wc,
                     const int* __restrict__ flag,
                     unsigned short* __restrict__ Qf,
                     unsigned short* __restrict__ Kf,
                     unsigned short* __restrict__ Vf)
{
    __shared__ __align__(16) unsigned short SMEM[4][4096];   // 32 KB

    const int isf32 = *flag;
    const unsigned short* Xb = isf32 ? Xc : (const unsigned short*)Xo;
    const unsigned short* Wb = isf32 ? Wc : (const unsigned short*)Wo_;

    const int tid  = threadIdx.x;
    const int lane = tid & 63;
    const int wave = tid >> 6;
    const int wr = wave >> 1, wc = wave & 1;
    const int lm = lane & 15, q4 = lane >> 4;
    const int rbase = blockIdx.y * 128;   // n
    const int cbase = blockIdx.x * 128;   // e

    const int srow = wave * 16 + (lane >> 2);
    const int scol = (lane & 3) * 8;

    const unsigned short* xsrc = Xb + (size_t)(rbase + srow) * DIM + scol;
    const unsigned short* wsrc = Wb + (size_t)(cbase + srow) * DIM + scol;
    const int la = (wr*64 + lm)*32 + q4*8;
    const int lb = (wc*64 + lm)*32 + q4*8;

    f32x4 acc[4][4];
    #pragma unroll
    for (int i = 0; i < 4; ++i)
        #pragma unroll
        for (int j = 0; j < 4; ++j) acc[i][j] = (f32x4){0.f, 0.f, 0.f, 0.f};

    #define QSTAGE(buf)                                                             \
        {                                                                           \
            _Pragma("unroll")                                                       \
            for (int j = 0; j < 2; ++j) {                                           \
                gload_lds16(xsrc + (size_t)j*64*DIM, &SMEM[buf][j*2048 + wave*512]);   \
                gload_lds16(wsrc + (size_t)j*64*DIM, &SMEM[2+buf][j*2048 + wave*512]); \
            }                                                                       \
            xsrc += 32; wsrc += 32;                                                 \
        }

    QSTAGE(0)
    for (int it = 0; it < DIM/32; ++it) {
        const int cur = it & 1;
        __syncthreads();
        if (it + 1 < DIM/32) QSTAGE(cur ^ 1)

        bf16x8 a[4], b[4];
        #pragma unroll
        for (int mi = 0; mi < 4; ++mi)
            a[mi] = *(const bf16x8*)&SMEM[cur][la + mi*512];
        #pragma unroll
        for (int ni = 0; ni < 4; ++ni)
            b[ni] = *(const bf16x8*)&SMEM[2+cur][lb + ni*512];
        #pragma unroll
        for (int mi = 0; mi < 4; ++mi)
            #pragma unroll
            for (int ni = 0; ni < 4; ++ni)
                acc[mi][ni] = mfma16(a[mi], b[ni], acc[mi][ni]);
    }
    #undef QSTAGE

    __syncthreads();   // staging LDS now free for epilogue transpose

    const int ecol = cbase + wc * 64;
    const int part = ecol >> 10;            // 0=q, 1=k, 2=v
    const int h    = (ecol >> 6) & 15;
    unsigned short* ep = &SMEM[0][0] + wave*4096;

    if (part == 2) {
        #pragma unroll
        for (int mh = 0; mh < 2; ++mh) {
            #pragma unroll
            for (int mi2 = 0; mi2 < 2; ++mi2) {
                const int mi = mh*2 + mi2;
                #pragma unroll
                for (int r = 0; r < 4; ++r) {
                    const int n31 = mi2*16 + q4*4 + r;
                    #pragma unroll
                    for (int ni = 0; ni < 4; ++ni)
                        ep[(ni*16 + lm)*40 + n31] = f2bf_fast(acc[mi][ni][r]);
                }
            }
            const int nb = rbase + wr*64 + mh*32;
            const size_t vb = (((size_t)h*128 + (nb >> 5)) << 11) + (size_t)lane*8;
            #pragma unroll
            for (int ni = 0; ni < 4; ++ni) {
                const bf16x8 fr = *(const bf16x8*)(ep + (ni*16 + lm)*40 + q4*8);
                *(bf16x8*)(Vf + vb + (size_t)ni*512) = fr;
            }
        }
    } else {
        unsigned short* dst = (part == 0) ? Qf : Kf;
        const float scl = (part == 0) ? 0.180336884f : 1.0f;   // log2(e)/8 folded into Q
        // frequency in REVOLUTIONS: 10000^(-d/32) / (2*pi)
        const float r2pi = 0.15915494309f;
        const float inv0 = powf(10000.f, -((float)lm)        * (1.f/32.f)) * r2pi;
        const float inv1 = powf(10000.f, -((float)(lm + 16)) * (1.f/32.f)) * r2pi;
        #pragma unroll
        for (int mi = 0; mi < 4; ++mi) {
            const int tn = rbase + wr*64 + mi*16;
            #pragma unroll
            for (int r = 0; r < 4; ++r) {
                const int n = tn + q4*4 + r;
                float s0, c0, s1, c1;
                hsincos_rev((float)n * inv0, &s0, &c0);
                hsincos_rev((float)n * inv1, &s1, &c1);
                const int row = (q4*4 + r)*72;
                ep[row + lm]      = f2bf_fast((acc[mi][0][r]*c0 - acc[mi][2][r]*s0) * scl);
                ep[row + lm + 16] = f2bf_fast((acc[mi][1][r]*c1 - acc[mi][3][r]*s1) * scl);
                ep[row + lm + 32] = f2bf_fast((acc[mi][2][r]*c0 + acc[mi][0][r]*s0) * scl);
                ep[row + lm + 48] = f2bf_fast((acc[mi][3][r]*c1 + acc[mi][1][r]*s1) * scl);
            }
            const size_t tb = (((size_t)(h*256 + (tn >> 4))) << 10) + (size_t)lane*8;
            #pragma unroll
            for (int c = 0; c < 2; ++c) {
                const bf16x8 fr = *(const bf16x8*)(ep + lm*72 + c*32 + q4*8);
                *(bf16x8*)(dst + tb + (size_t)c*512) = fr;
            }
        }
    }
}

// ---------------------------------------------------------------------------
// Kernel 2: MFMA flash attention — r12 (2x2 wave split, dbuf staging,
// LPT order) frozen; only epilogue pack switched to fast.
// ---------------------------------------------------------------------------
__global__ __launch_bounds__(256)
void attn_mfma_kernel(const unsigned short* __restrict__ Qf,
                      const unsigned short* __restrict__ Kf,
                      const unsigned short* __restrict__ Vf,
                      unsigned short* __restrict__ Attn)
{
    __shared__ __align__(16) unsigned short Ks[2][4096];     // 16 KB (reused as Ox)
    __shared__ __align__(16) unsigned short Vs[2][4096];     // 16 KB (reused as Lx)
    __shared__ __align__(16) unsigned short P16[4][32][40];  // 10 KB

    const int tid  = threadIdx.x;
    const int lane = tid & 63;
    const int wave = tid >> 6;
    const int q4 = lane >> 4, lm = lane & 15;
    const int qh = wave >> 1, kh = wave & 1;

    const int h  = blockIdx.x & 15;
    const int qb = blockIdx.x >> 4;
    const int q0 = (63 - qb) << 6;             // LPT: heavy blocks first
    const int qw = q0 + (qh << 5);             // this wave's 32 queries

    const unsigned short* qp = Qf + (((size_t)(h*256 + (qw >> 4))) << 10) + (size_t)lane * 8;
    bf16x8 aq[2][2];
    aq[0][0] = *(const bf16x8*)(qp);
    aq[0][1] = *(const bf16x8*)(qp + 512);
    aq[1][0] = *(const bf16x8*)(qp + 1024);
    aq[1][1] = *(const bf16x8*)(qp + 1536);

    float l_part[2][4];
    f32x4 o[2][4];
    #pragma unroll
    for (int qi = 0; qi < 2; ++qi) {
        #pragma unroll
        for (int r = 0; r < 4; ++r) l_part[qi][r] = 0.f;
        #pragma unroll
        for (int dc = 0; dc < 4; ++dc) o[qi][dc] = (f32x4){0.f, 0.f, 0.f, 0.f};
    }

    const unsigned short* sbase;
    unsigned short* db0;
    unsigned short* db1;
    {
        const int ch0 = (wave & 1) * 4;
        const size_t hb = ((size_t)h) << 18;
        sbase = ((wave < 2) ? Kf : Vf) + hb + ch0*512 + (size_t)lane*8;
        db0 = ((wave < 2) ? &Ks[0][0] : &Vs[0][0]) + ch0*512;
        db1 = ((wave < 2) ? &Ks[1][0] : &Vs[1][0]) + ch0*512;
    }
    unsigned short* pw  = &P16[wave][0][0];
    unsigned short* pwa = pw + (4*q4)*40 + lm;
    const unsigned short* par = pw + lm*40 + q4*8;

    const int ntiles = (q0 >> 6) + 1;

    #define STAGE(dst)                                                         \
        {                                                                      \
            _Pragma("unroll")                                                  \
            for (int i = 0; i < 4; ++i)                                        \
                gload_lds16(sbase + i*512, (dst) + i*512);                     \
            sbase += 4096;                                                     \
        }

    STAGE(db0)

    for (int it = 0; it < ntiles; ++it) {
        const int kt = it << 6;
        const int cur = it & 1;

        __syncthreads();
        if (it + 1 < ntiles) STAGE(cur ? db0 : db1)

        const unsigned short* kc = &Ks[cur][kh*2048 + lane*8];
        const unsigned short* vc = &Vs[cur][kh*2048 + lane*8];

        f32x4 s[2][2];
        #pragma unroll
        for (int ki = 0; ki < 2; ++ki) {
            const bf16x8 bk0 = *(const bf16x8*)(kc + ki*1024);
            const bf16x8 bk1 = *(const bf16x8*)(kc + ki*1024 + 512);
            #pragma unroll
            for (int qi = 0; qi < 2; ++qi) {
                f32x4 z = (f32x4){0.f, 0.f, 0.f, 0.f};
                z = mfma16(aq[qi][0], bk0, z);
                s[qi][ki] = mfma16(aq[qi][1], bk1, z);
            }
        }

        if (kt + 32*kh + 31 > qw) {
            #pragma unroll
            for (int ki = 0; ki < 2; ++ki) {
                const int key = kt + 32*kh + 16*ki + lm;
                #pragma unroll
                for (int qi = 0; qi < 2; ++qi) {
                    const int qq = qw + 16*qi + 4*q4;
                    #pragma unroll
                    for (int r = 0; r < 4; ++r)
                        if (key > qq + r) s[qi][ki][r] = -INFINITY;
                }
            }
        }

        #pragma unroll
        for (int qi = 0; qi < 2; ++qi)
            #pragma unroll
            for (int ki = 0; ki < 2; ++ki)
                #pragma unroll
                for (int r = 0; r < 4; ++r) {
                    const float p = EXP2(s[qi][ki][r]);
                    l_part[qi][r] += p;
                    pwa[qi*640 + r*40 + ki*16] = f2bf_fast(p);
                }

        bf16x8 pa[2];
        pa[0] = *(const bf16x8*)(par);
        pa[1] = *(const bf16x8*)(par + 640);

        #pragma unroll
        for (int dc = 0; dc < 4; ++dc) {
            const bf16x8 bv = *(const bf16x8*)(vc + dc*512);
            #pragma unroll
            for (int qi = 0; qi < 2; ++qi)
                o[qi][dc] = mfma16(pa[qi], bv, o[qi][dc]);
        }
    }
    #undef STAGE

    #pragma unroll
    for (int qi = 0; qi < 2; ++qi)
        #pragma unroll
        for (int r = 0; r < 4; ++r) {
            float l = l_part[qi][r];
            #pragma unroll
            for (int mk = 1; mk <= 8; mk <<= 1) l += __shfl_xor(l, mk);
            l_part[qi][r] = l;
        }

    float* Ox = (float*)&Ks[0][0];
    float* Lx = (float*)&Vs[0][0];
    __syncthreads();
    if (kh == 1) {
        #pragma unroll
        for (int qi = 0; qi < 2; ++qi) {
            #pragma unroll
            for (int r = 0; r < 4; ++r) {
                const int qq = 16*qi + 4*q4 + r;
                #pragma unroll
                for (int dc = 0; dc < 4; ++dc)
                    Ox[qh*2048 + qq*64 + 16*dc + lm] = o[qi][dc][r];
                if (lm == 0) Lx[qh*32 + qq] = l_part[qi][r];
            }
        }
    }
    __syncthreads();
    if (kh == 0) {
        #pragma unroll
        for (int qi = 0; qi < 2; ++qi)
            #pragma unroll
            for (int r = 0; r < 4; ++r) {
                const int qq = 16*qi + 4*q4 + r;
                const float inv = 1.f / (l_part[qi][r] + Lx[qh*32 + qq]);
                const size_t row = (size_t)(qw + qq) * DIM + (h << 6) + lm;
                #pragma unroll
                for (int dc = 0; dc < 4; ++dc) {
                    const float v = o[qi][dc][r] + Ox[qh*2048 + qq*64 + 16*dc + lm];
                    Attn[row + 16*dc] = f2bf_fast(v * inv);
                }
            }
    }
}

// ---------------------------------------------------------------------------
// Kernel 3: out projection, MFMA, 128x64 tiles + dbuf staging (proven).
// ---------------------------------------------------------------------------
__global__ __launch_bounds__(256)
void out_mfma_kernel(const unsigned short* __restrict__ Ab,
                     const void* __restrict__ Wo_, const unsigned short* __restrict__ Wc,
                     const int* __restrict__ flag,
                     void* __restrict__ Out)
{
    __shared__ unsigned short As[2][4096];   // 16 KB
    __shared__ unsigned short Bs[2][2048];   // 8 KB

    const int isf32 = *flag;
    const unsigned short* Wb = isf32 ? Wc : (const unsigned short*)Wo_;

    const int tid  = threadIdx.x;
    const int lane = tid & 63;
    const int wave = tid >> 6;
    const int lm = lane & 15, q4 = lane >> 4;
    const int rbase = blockIdx.y * 128;
    const int cbase = blockIdx.x * 64;

    const int srow16 = lane >> 2;
    const int scol = (lane & 3) * 8;

    const unsigned short* asrc = Ab + (size_t)(rbase + wave*32 + srow16) * DIM + scol;
    const unsigned short* bsrc = Wb + (size_t)(cbase + wave*16 + srow16) * DIM + scol;
    const int la = (wave*32 + lm)*32 + q4*8;
    const int lb = lm*32 + q4*8;

    f32x4 acc[2][4];
    #pragma unroll
    for (int i = 0; i < 2; ++i)
        #pragma unroll
        for (int j = 0; j < 4; ++j) acc[i][j] = (f32x4){0.f, 0.f, 0.f, 0.f};

    #define OSTAGE(buf)                                                          \
        {                                                                        \
            _Pragma("unroll")                                                    \
            for (int j = 0; j < 2; ++j)                                          \
                gload_lds16(asrc + (size_t)j*16*DIM, &As[buf][(wave*32 + j*16)*32]); \
            gload_lds16(bsrc, &Bs[buf][(wave*16)*32]);                           \
            asrc += 32; bsrc += 32;                                              \
        }

    OSTAGE(0)
    for (int it = 0; it < DIM/32; ++it) {
        const int cur = it & 1;
        __syncthreads();
        if (it + 1 < DIM/32) OSTAGE(cur ^ 1)

        bf16x8 a[2], b[4];
        #pragma unroll
        for (int mi = 0; mi < 2; ++mi)
            a[mi] = *(const bf16x8*)&As[cur][la + mi*512];
        #pragma unroll
        for (int ni = 0; ni < 4; ++ni)
            b[ni] = *(const bf16x8*)&Bs[cur][lb + ni*512];
        #pragma unroll
        for (int mi = 0; mi < 2; ++mi)
            #pragma unroll
            for (int ni = 0; ni < 4; ++ni)
                acc[mi][ni] = mfma16(a[mi], b[ni], acc[mi][ni]);
    }
    #undef OSTAGE

    #pragma unroll
    for (int mi = 0; mi < 2; ++mi)
        #pragma unroll
        for (int r = 0; r < 4; ++r) {
            const size_t n = rbase + wave*32 + mi*16 + q4*4 + r;
            #pragma unroll
            for (int ni = 0; ni < 4; ++ni) {
                const size_t e = cbase + ni*16 + lm;
                const float v = acc[mi][ni][r];
                if (isf32) ((float*)Out)[n * DIM + e] = v;
                else       ((unsigned short*)Out)[n * DIM + e] = f2bf(v);
            }
        }
}

// ---------------------------------------------------------------------------
extern "C" void kernel_launch(void* const* d_in, const int* in_sizes, int n_in,
                              void* d_out, int out_size, void* d_ws, size_t ws_size,
                              hipStream_t stream) {
    const void* X    = d_in[0];
    const void* Wqkv = d_in[1];
    const void* Wout = d_in[2];

    int* flag = (int*)d_ws;
    unsigned short* base = (unsigned short*)((char*)d_ws + 256);
    const size_t nX = (size_t)N_SEQ * DIM;
    const size_t nWq = (size_t)E3 * DIM;
    const size_t nWo = (size_t)DIM * DIM;
    unsigned short* Xb  = base;
    unsigned short* Wqb = Xb + nX;
    unsigned short* Wob = Wqb + nWq;
    unsigned short* Qf  = Wob + nWo;
    unsigned short* Kf  = Qf + nX;
    unsigned short* Vf  = Kf + nX;
    unsigned short* At  = Vf + nX;

    prep_kernel<<<768, 256, 0, stream>>>(X, Wqkv, Wout, Xb, Wqb, Wob, flag);
    qkv_mfma_kernel<<<dim3(E3 / 128, N_SEQ / 128), 256, 0, stream>>>(X, Xb, Wqkv, Wqb, flag, Qf, Kf, Vf);
    attn_mfma_kernel<<<dim3(NHEAD * (N_SEQ / 64)), 256, 0, stream>>>(Qf, Kf, Vf, At);
    out_mfma_kernel<<<dim3(DIM / 64, N_SEQ / 128), 256, 0, stream>>>(At, Wout, Wob, flag, d_out);
}